// Round 19
// baseline (633.698 us; speedup 1.0000x reference)
//
#include <hip/hip_runtime.h>
#include <math.h>

#define NBUS 30000
#define NGEN 6000
#define NEL 250000
#define NEG 12000

#define AS1 __attribute__((address_space(1)))
#define AS3 __attribute__((address_space(3)))

typedef unsigned short u16;
typedef __attribute__((ext_vector_type(8))) short bf16x8;
typedef __attribute__((ext_vector_type(4))) float f32x4;

__device__ __forceinline__ u16 f2b(float x) {  // fp32 -> bf16 RNE
  unsigned u = __float_as_uint(x);
  unsigned r = (u + 0x7FFFu + ((u >> 16) & 1u)) >> 16;
  return (u16)r;
}
__device__ __forceinline__ float b2f(u16 x) {
  return __uint_as_float((unsigned)x << 16);
}

__global__ void zeroi(int* __restrict__ p, int n) {
  int i = blockIdx.x * blockDim.x + threadIdx.x;
  int st = gridDim.x * blockDim.x;
  for (; i < n; i += st) p[i] = 0;
}

__global__ void cast_k(const float* __restrict__ s, u16* __restrict__ d, int n) {
  int i = blockIdx.x * 256 + threadIdx.x;
  if (i < n) d[i] = f2b(s[i]);
}

// ---------------- batched CSR build over 3 edge types ----------------
struct CsrArgs {
  const int* dst[3];
  const int* src[3];
  const float* ea[3];
  int* cnt[3];      // histogram; later reused as scatter cursor
  int* rowptr[3];
  int* eidx[3];
  int* srcC[3];
  float* eaC[3];
  int* psum[3];
  int E[3];
  int N[3];
};

__global__ void hist_b(CsrArgs a) {
  int ty = blockIdx.y;
  int i = blockIdx.x * 256 + threadIdx.x;
  if (i < a.E[ty]) atomicAdd(&a.cnt[ty][a.dst[ty][i]], 1);
}

__global__ __launch_bounds__(1024) void scan_p1(CsrArgs a) {
  int ty = blockIdx.y;
  int n = a.N[ty];
  int base = blockIdx.x * 1024;
  if (base >= n) return;
  int tid = threadIdx.x, lane = tid & 63, wv = tid >> 6;
  int i = base + tid;
  int v = (i < n) ? a.cnt[ty][i] : 0;
#pragma unroll
  for (int off = 32; off >= 1; off >>= 1) v += __shfl_xor(v, off);
  __shared__ int w[16];
  if (lane == 0) w[wv] = v;
  __syncthreads();
  if (tid < 16) {
    int t = w[tid];
#pragma unroll
    for (int off = 8; off >= 1; off >>= 1) t += __shfl_xor(t, off, 16);
    if (tid == 0) a.psum[ty][blockIdx.x] = t;
  }
}

__global__ __launch_bounds__(64) void scan_p2(CsrArgs a) {
  int ty = blockIdx.y;
  int nb = (a.N[ty] + 1023) / 1024;
  int tid = threadIdx.x;
  int v = (tid < nb) ? a.psum[ty][tid] : 0;
  int x = v;
#pragma unroll
  for (int off = 1; off < 64; off <<= 1) {
    int y = __shfl_up(x, off, 64);
    if (tid >= off) x += y;
  }
  if (tid < nb) a.psum[ty][tid] = x - v;  // exclusive
}

__global__ __launch_bounds__(1024) void scan_p3(CsrArgs a) {
  int ty = blockIdx.y;
  int n = a.N[ty];
  int base = blockIdx.x * 1024;
  if (base >= n) return;
  int tid = threadIdx.x, lane = tid & 63, wv = tid >> 6;
  int i = base + tid;
  int v = (i < n) ? a.cnt[ty][i] : 0;
  int x = v;
#pragma unroll
  for (int off = 1; off < 64; off <<= 1) {
    int y = __shfl_up(x, off, 64);
    if (lane >= off) x += y;
  }
  __shared__ int w[16];
  if (lane == 63) w[wv] = x;
  __syncthreads();
  if (tid < 16) {
    int t = w[tid];
#pragma unroll
    for (int off = 1; off < 16; off <<= 1) {
      int y = __shfl_up(t, off, 16);
      if (tid >= off) t += y;
    }
    w[tid] = t;
  }
  __syncthreads();
  int woff = (wv == 0) ? 0 : w[wv - 1];
  int incl = a.psum[ty][blockIdx.x] + woff + x;
  if (i < n) {
    a.rowptr[ty][i + 1] = incl;
    a.cnt[ty][i] = incl - v;  // cursor (exclusive)
  }
  if (i == 0) a.rowptr[ty][0] = 0;
}

__global__ void scatter_b(CsrArgs a) {
  int ty = blockIdx.y;
  int i = blockIdx.x * 256 + threadIdx.x;
  if (i < a.E[ty]) {
    int p = atomicAdd(&a.cnt[ty][a.dst[ty][i]], 1);
    a.eidx[ty][p] = i;
  }
}

__global__ void gather_b(CsrArgs a) {
  int ty = blockIdx.y;
  int i = blockIdx.x * 256 + threadIdx.x;
  if (i >= a.E[ty]) return;
  int e = a.eidx[ty][i];
  a.srcC[ty][i] = a.src[ty][e];
  const float* s = a.ea[ty] + (size_t)e * 6;
  float* d = a.eaC[ty] + (size_t)i * 8;
  float e3 = s[3];
  d[0] = s[0]; d[1] = s[1]; d[2] = s[2]; d[3] = e3; d[4] = s[4];
  d[5] = 1.f / fmaxf(e3, 1e-6f);
}

// ---------------- projections ----------------
__global__ void gen_proj(const float* __restrict__ x, const float* __restrict__ w,
                         const float* __restrict__ b, u16* __restrict__ o16) {
  int idx = blockIdx.x * blockDim.x + threadIdx.x;
  if (idx >= NGEN * 32) return;
  int i = idx >> 5, c = idx & 31;
  float acc = b[c];
#pragma unroll
  for (int k = 0; k < 16; ++k) acc += x[i * 16 + k] * w[k * 32 + c];
  o16[idx] = f2b(acc);
}

struct PackArgs {
  const float* src[24];
  int off[24];
  int lgN[24];
  int total[24];
  int K[24];
};
__global__ void pack_multi(PackArgs a, u16* __restrict__ Wt) {
  int j = blockIdx.y;
  int idx = blockIdx.x * 256 + threadIdx.x;
  if (idx >= a.total[j]) return;
  int N1 = (1 << a.lgN[j]) - 1;
  int n = idx & N1;
  int k = idx >> a.lgN[j];
  Wt[(size_t)a.off[j] + (size_t)n * a.K[j] + k] = f2b(a.src[j][idx]);
}

// Merged bus+gen GEMM: global_load_lds w=16, XOR swizzle.
__global__ __launch_bounds__(256) void gemm_both(
    const u16* __restrict__ Ab, const u16* __restrict__ Ag,
    const u16* __restrict__ Wt, int goff,
    u16* __restrict__ Cb, u16* __restrict__ Cg,
    int K, int Nb, int Ng, int ybus)
{
  __shared__ __align__(16) u16 As[128 * 32];
  __shared__ __align__(16) u16 Bs[128 * 32];
  const int t = threadIdx.x;
  const int w = t >> 6, lane = t & 63;
  const u16* A; const u16* W; u16* C; int M, Ncols, bn;
  if ((int)blockIdx.y < ybus) {
    A = Ab; W = Wt; C = Cb; M = NBUS; Ncols = Nb; bn = blockIdx.y * 128;
  } else {
    A = Ag; W = Wt + goff; C = Cg; M = NGEN; Ncols = Ng; bn = (blockIdx.y - ybus) * 128;
  }
  const int bm = blockIdx.x * 128;
  if (bm >= M) return;
  const int wm = (w & 1) * 64, wn = (w >> 1) * 64;
  const int lr = lane & 15, q = lane >> 4;
  const int srow = lane >> 2;
  const int blk = (lane & 3) ^ (srow & 3);
  f32x4 acc[4][4] = {};
  for (int k0 = 0; k0 < K; k0 += 32) {
#pragma unroll
    for (int sseg = 0; sseg < 2; ++sseg) {
      int seg = w + (sseg << 2);
      int row = (seg << 4) + srow;
      int ga = bm + row; if (ga > M - 1) ga = M - 1;
      const u16* gpa = A + (size_t)ga * K + k0 + (blk << 3);
      __builtin_amdgcn_global_load_lds((AS1 void*)gpa, (AS3 void*)(As + (seg << 9)),
                                       16, 0, 0);
      int gb = bn + row;
      const u16* gpb = W + (size_t)gb * K + k0 + (blk << 3);
      __builtin_amdgcn_global_load_lds((AS1 void*)gpb, (AS3 void*)(Bs + (seg << 9)),
                                       16, 0, 0);
    }
    __syncthreads();
    bf16x8 af[4], bg[4];
#pragma unroll
    for (int i = 0; i < 4; ++i) {
      int r = wm + i * 16 + lr;
      af[i] = *(const bf16x8*)&As[(r << 5) + ((q ^ (r & 3)) << 3)];
    }
#pragma unroll
    for (int j = 0; j < 4; ++j) {
      int r = wn + j * 16 + lr;
      bg[j] = *(const bf16x8*)&Bs[(r << 5) + ((q ^ (r & 3)) << 3)];
    }
#pragma unroll
    for (int i = 0; i < 4; ++i)
#pragma unroll
      for (int j = 0; j < 4; ++j)
        acc[i][j] = __builtin_amdgcn_mfma_f32_16x16x32_bf16(
            af[i], bg[j], acc[i][j], 0, 0, 0);
    __syncthreads();
  }
#pragma unroll
  for (int i = 0; i < 4; ++i) {
    int row0 = bm + wm + i * 16 + q * 4;
#pragma unroll
    for (int j = 0; j < 4; ++j) {
      int col = bn + wn + j * 16 + lr;
      if (col < Ncols) {
#pragma unroll
        for (int r = 0; r < 4; ++r) {
          int row = row0 + r;
          if (row < M) C[(size_t)row * Ncols + col] = f2b(acc[i][j][r]);
        }
      }
    }
  }
}

// ---------------- fused GATv2 conv (online softmax, 3-state ILP) ----------------
__device__ __forceinline__ f32x4 conv_set(
    int node, int lane, const int* __restrict__ rp,
    const int* __restrict__ srcc, const float* __restrict__ eac,
    const u16* __restrict__ xl, int ldl,
    const u16* __restrict__ xr, int ldr,
    const float* __restrict__ We, const float* __restrict__ att,
    const float* __restrict__ tptr)
{
  int c0 = lane << 2;
  float4 w0 = *(const float4*)(We + c0);
  float4 w1 = *(const float4*)(We + 256 + c0);
  float4 w2 = *(const float4*)(We + 512 + c0);
  float4 w3 = *(const float4*)(We + 768 + c0);
  float4 w4 = *(const float4*)(We + 1024 + c0);
  float4 w5 = *(const float4*)(We + 1280 + c0);
  float4 av = *(const float4*)(att + c0);
  float temp = *tptr;
  ushort4 r16 = *(const ushort4*)(xr + (size_t)node * ldr + c0);
  float rx0 = b2f(r16.x), rx1 = b2f(r16.y), rx2 = b2f(r16.z), rx3 = b2f(r16.w);
  int beg = rp[node], end = rp[node + 1];
  float mx0 = -INFINITY, dn0 = 0.f;
  float mx1 = -INFINITY, dn1 = 0.f;
  float mx2 = -INFINITY, dn2 = 0.f;
  f32x4 ac0 = {0.f, 0.f, 0.f, 0.f};
  f32x4 ac1 = {0.f, 0.f, 0.f, 0.f};
  f32x4 ac2 = {0.f, 0.f, 0.f, 0.f};

  auto edge_upd = [&](int i, float& mx, float& den, f32x4& acc) {
    int s = srcc[i];
    const float* e = eac + (size_t)i * 8;
    float4 ev = *(const float4*)e;
    float2 e2v = *(const float2*)(e + 4);
    float e5 = temp * e2v.y;
    ushort4 l16 = *(const ushort4*)(xl + (size_t)s * ldl + c0);
    float lx0 = b2f(l16.x), lx1 = b2f(l16.y), lx2 = b2f(l16.z), lx3 = b2f(l16.w);
    float m0 = lx0 + rx0 + ev.x*w0.x + ev.y*w1.x + ev.z*w2.x + ev.w*w3.x + e2v.x*w4.x + e5*w5.x;
    float m1 = lx1 + rx1 + ev.x*w0.y + ev.y*w1.y + ev.z*w2.y + ev.w*w3.y + e2v.x*w4.y + e5*w5.y;
    float m2 = lx2 + rx2 + ev.x*w0.z + ev.y*w1.z + ev.z*w2.z + ev.w*w3.z + e2v.x*w4.z + e5*w5.z;
    float m3 = lx3 + rx3 + ev.x*w0.w + ev.y*w1.w + ev.z*w2.w + ev.w*w3.w + e2v.x*w4.w + e5*w5.w;
    m0 = fmaxf(m0, 0.2f * m0);
    m1 = fmaxf(m1, 0.2f * m1);
    m2 = fmaxf(m2, 0.2f * m2);
    m3 = fmaxf(m3, 0.2f * m3);
    float p = m0*av.x + m1*av.y + m2*av.z + m3*av.w;
    p += __shfl_xor(p, 1);
    p += __shfl_xor(p, 2);
    p += __shfl_xor(p, 4);
    p += __shfl_xor(p, 8);
    float nm = fmaxf(mx, p);
    float sc = __expf(mx - nm);
    float wq = __expf(p - nm);
    mx = nm;
    den = den * sc + wq;
    acc[0] = acc[0] * sc + wq * lx0;
    acc[1] = acc[1] * sc + wq * lx1;
    acc[2] = acc[2] * sc + wq * lx2;
    acc[3] = acc[3] * sc + wq * lx3;
  };

  int i = beg;
  for (; i + 3 <= end; i += 3) {
    edge_upd(i, mx0, dn0, ac0);
    edge_upd(i + 1, mx1, dn1, ac1);
    edge_upd(i + 2, mx2, dn2, ac2);
  }
  if (i < end) { edge_upd(i, mx0, dn0, ac0); ++i; }
  if (i < end) { edge_upd(i, mx1, dn1, ac1); }

  float nm = fmaxf(fmaxf(mx0, mx1), mx2);
  f32x4 r = {0.f, 0.f, 0.f, 0.f};
  if (nm > -INFINITY) {
    float s0 = __expf(mx0 - nm), s1 = __expf(mx1 - nm), s2 = __expf(mx2 - nm);
    float den = dn0 * s0 + dn1 * s1 + dn2 * s2;
    float inv = 1.f / (den + 1e-16f);
    r[0] = (ac0[0] * s0 + ac1[0] * s1 + ac2[0] * s2) * inv;
    r[1] = (ac0[1] * s0 + ac1[1] * s1 + ac2[1] * s2) * inv;
    r[2] = (ac0[2] * s0 + ac1[2] * s1 + ac2[2] * s2) * inv;
    r[3] = (ac0[3] * s0 + ac1[3] * s1 + ac2[3] * s2) * inv;
  }
  return r;
}

struct ConvP {
  const int *rpA, *srcA; const float* eaA;
  const u16 *xlA; int ldlA; const u16 *xrA; int ldrA;
  const float *WeA, *attA, *tA;
  const int *rpB, *srcB; const float* eaB;
  const u16 *xlB; int ldlB; const u16 *xrB; int ldrB;
  const float *WeB, *attB, *tB;
  const float *b1, *b2;        // conv bias(es)
  const float *lnw, *lnb;
  const u16 *res16; int ld16;  // bf16 residual (P column or state buffer)
  float *outf;                 // MODE1: d_out base
  u16 *out16;                  // MODE0: bf16 state out
  int N;
};

// MODE 0: LN256 + bf16-residual + ELU, write bf16 state.
// MODE 1: head-mean + LN64 + bf16-residual, write d_out (fp32).
template<int MODE, int HASB>
__global__ __launch_bounds__(256) void conv_fused(ConvP p) {
  int node = blockIdx.x * 4 + (threadIdx.x >> 6);
  int lane = threadIdx.x & 63;
  if (node >= p.N) return;
  f32x4 o = conv_set(node, lane, p.rpA, p.srcA, p.eaA, p.xlA, p.ldlA,
                     p.xrA, p.ldrA, p.WeA, p.attA, p.tA);
  if (HASB) {
    if (p.rpB[node] < p.rpB[node + 1]) {  // skip empty set-B (uniform branch)
      f32x4 ob = conv_set(node, lane, p.rpB, p.srcB, p.eaB, p.xlB, p.ldlB,
                          p.xrB, p.ldrB, p.WeB, p.attB, p.tB);
      o[0] += ob[0]; o[1] += ob[1]; o[2] += ob[2]; o[3] += ob[3];
    }
  }
  if (MODE == 0) {
    int c = lane << 2;
    float4 bb = *(const float4*)(p.b1 + c);
    float v0 = o[0] + bb.x, v1 = o[1] + bb.y, v2 = o[2] + bb.z, v3 = o[3] + bb.w;
    if (p.b2) {
      float4 b2v = *(const float4*)(p.b2 + c);
      v0 += b2v.x; v1 += b2v.y; v2 += b2v.z; v3 += b2v.w;
    }
    float s = v0 + v1 + v2 + v3;
#pragma unroll
    for (int m = 32; m >= 1; m >>= 1) s += __shfl_xor(s, m);
    float mu = s * (1.f / 256.f);
    float d0 = v0 - mu, d1 = v1 - mu, d2 = v2 - mu, d3 = v3 - mu;
    float q = d0*d0 + d1*d1 + d2*d2 + d3*d3;
#pragma unroll
    for (int m = 32; m >= 1; m >>= 1) q += __shfl_xor(q, m);
    float rs = rsqrtf(q * (1.f / 256.f) + 1e-5f);
    float4 lw = *(const float4*)(p.lnw + c);
    float4 lb = *(const float4*)(p.lnb + c);
    float y0 = d0 * rs * lw.x + lb.x;
    float y1 = d1 * rs * lw.y + lb.y;
    float y2 = d2 * rs * lw.z + lb.z;
    float y3 = d3 * rs * lw.w + lb.w;
    ushort4 r = *(const ushort4*)(p.res16 + (size_t)node * p.ld16 + c);
    y0 += b2f(r.x); y1 += b2f(r.y); y2 += b2f(r.z); y3 += b2f(r.w);
    y0 = (y0 > 0.f) ? y0 : expm1f(y0);
    y1 = (y1 > 0.f) ? y1 : expm1f(y1);
    y2 = (y2 > 0.f) ? y2 : expm1f(y2);
    y3 = (y3 > 0.f) ? y3 : expm1f(y3);
    ushort4 o16;
    o16.x = f2b(y0); o16.y = f2b(y1); o16.z = f2b(y2); o16.w = f2b(y3);
    *(ushort4*)(p.out16 + (size_t)node * 256 + c) = o16;
  } else {
    // head mean: sum over the 4 head groups (lanes xor 16, 32)
    float h0 = o[0], h1 = o[1], h2 = o[2], h3 = o[3];
    h0 += __shfl_xor(h0, 16); h0 += __shfl_xor(h0, 32);
    h1 += __shfl_xor(h1, 16); h1 += __shfl_xor(h1, 32);
    h2 += __shfl_xor(h2, 16); h2 += __shfl_xor(h2, 32);
    h3 += __shfl_xor(h3, 16); h3 += __shfl_xor(h3, 32);
    int cc = (lane & 15) << 2;
    float4 bb = *(const float4*)(p.b1 + cc);
    float v0 = 0.25f * h0 + bb.x, v1 = 0.25f * h1 + bb.y;
    float v2 = 0.25f * h2 + bb.z, v3 = 0.25f * h3 + bb.w;
    if (p.b2) {
      float4 b2v = *(const float4*)(p.b2 + cc);
      v0 += b2v.x; v1 += b2v.y; v2 += b2v.z; v3 += b2v.w;
    }
    float s = v0 + v1 + v2 + v3;
#pragma unroll
    for (int m = 8; m >= 1; m >>= 1) s += __shfl_xor(s, m);
    float mu = s * (1.f / 64.f);
    float d0 = v0 - mu, d1 = v1 - mu, d2 = v2 - mu, d3 = v3 - mu;
    float q = d0*d0 + d1*d1 + d2*d2 + d3*d3;
#pragma unroll
    for (int m = 8; m >= 1; m >>= 1) q += __shfl_xor(q, m);
    float rs = rsqrtf(q * (1.f / 64.f) + 1e-5f);
    float4 lw = *(const float4*)(p.lnw + cc);
    float4 lb = *(const float4*)(p.lnb + cc);
    ushort4 r = *(const ushort4*)(p.res16 + (size_t)node * p.ld16 + cc);
    float y0 = d0 * rs * lw.x + lb.x + b2f(r.x);
    float y1 = d1 * rs * lw.y + lb.y + b2f(r.y);
    float y2 = d2 * rs * lw.z + lb.z + b2f(r.z);
    float y3 = d3 * rs * lw.w + lb.w + b2f(r.w);
    if (lane < 16)
      *(float4*)(p.outf + (size_t)node * 64 + cc) = make_float4(y0, y1, y2, y3);
  }
}

extern "C" void kernel_launch(void* const* d_in, const int* in_sizes, int n_in,
                              void* d_out, int out_size, void* d_ws, size_t ws_size,
                              hipStream_t stream) {
  const float* x_bus = (const float*)d_in[0];
  const float* x_gen = (const float*)d_in[1];
  const float* ea[3] = {(const float*)d_in[2], (const float*)d_in[3], (const float*)d_in[4]};
  const float* pw = (const float*)d_in[5];
  const float* pb = (const float*)d_in[6];
  const float* Wl[3] = {(const float*)d_in[7], (const float*)d_in[15], (const float*)d_in[23]};
  const float* Wr[3] = {(const float*)d_in[8], (const float*)d_in[16], (const float*)d_in[24]};
  const float* We[3] = {(const float*)d_in[9], (const float*)d_in[17], (const float*)d_in[25]};
  const float* att[3] = {(const float*)d_in[10], (const float*)d_in[18], (const float*)d_in[26]};
  const float* bc[3] = {(const float*)d_in[11], (const float*)d_in[19], (const float*)d_in[27]};
  const float* temp[3] = {(const float*)d_in[12], (const float*)d_in[20], (const float*)d_in[28]};
  const float* lnw[3] = {(const float*)d_in[13], (const float*)d_in[21], (const float*)d_in[29]};
  const float* lnb[3] = {(const float*)d_in[14], (const float*)d_in[22], (const float*)d_in[30]};
  const float* rp0_w = (const float*)d_in[31];
  const float* rp2_w = (const float*)d_in[33];
  const int* srcs[3] = {(const int*)d_in[35], (const int*)d_in[37], (const int*)d_in[39]};
  const int* dsts[3] = {(const int*)d_in[36], (const int*)d_in[38], (const int*)d_in[40]};

  float* ws = (float*)d_ws;
  size_t off = 0;
  auto alloc = [&](size_t n) { float* p = ws + off; off += n; return p; };
  u16* xb16_0 = (u16*)alloc((size_t)NBUS * 16);
  u16* xg16_0 = (u16*)alloc((size_t)NGEN * 16);
  u16* xb16 = (u16*)alloc((size_t)NBUS * 128);
  u16* xg16 = (u16*)alloc((size_t)NGEN * 128);
  u16* Pbus = (u16*)alloc((size_t)NBUS * 640);
  u16* Pgen = (u16*)alloc((size_t)NGEN * 384);
  u16* Wt = (u16*)alloc((size_t)886000 / 2);  // 884736 packed elements + pad
  float* eaC0 = alloc((size_t)NEL * 8);
  float* eaC1 = alloc((size_t)NEG * 8);
  float* eaC2 = alloc((size_t)NEG * 8);
  int* cw_all = (int*)alloc(NBUS + NBUS + NGEN);  // 3 histograms, contiguous
  int* rp_line = (int*)alloc(NBUS + 1);
  int* rp_g2b = (int*)alloc(NBUS + 1);
  int* rp_b2g = (int*)alloc(NGEN + 1);
  int* ei_line = (int*)alloc(NEL);
  int* ei_g2b = (int*)alloc(NEG);
  int* ei_b2g = (int*)alloc(NEG);
  int* sc_line = (int*)alloc(NEL);
  int* sc_g2b = (int*)alloc(NEG);
  int* sc_b2g = (int*)alloc(NEG);
  int* psum = (int*)alloc(3 * 32);
  (void)ws_size; (void)in_sizes; (void)n_in; (void)out_size;

  CsrArgs ca;
  for (int t = 0; t < 3; ++t) { ca.dst[t] = dsts[t]; ca.src[t] = srcs[t]; ca.ea[t] = ea[t]; }
  ca.cnt[0] = cw_all; ca.cnt[1] = cw_all + NBUS; ca.cnt[2] = cw_all + 2 * NBUS;
  ca.rowptr[0] = rp_line; ca.rowptr[1] = rp_g2b; ca.rowptr[2] = rp_b2g;
  ca.eidx[0] = ei_line; ca.eidx[1] = ei_g2b; ca.eidx[2] = ei_b2g;
  ca.srcC[0] = sc_line; ca.srcC[1] = sc_g2b; ca.srcC[2] = sc_b2g;
  ca.eaC[0] = eaC0; ca.eaC[1] = eaC1; ca.eaC[2] = eaC2;
  ca.psum[0] = psum; ca.psum[1] = psum + 32; ca.psum[2] = psum + 64;
  ca.E[0] = NEL; ca.E[1] = NEG; ca.E[2] = NEG;
  ca.N[0] = NBUS; ca.N[1] = NBUS; ca.N[2] = NGEN;

  int egrid = (NEL + 255) / 256;
  hipLaunchKernelGGL(zeroi, dim3(64), dim3(1024), 0, stream, cw_all, 2 * NBUS + NGEN);
  hipLaunchKernelGGL(hist_b, dim3(egrid, 3), dim3(256), 0, stream, ca);
  hipLaunchKernelGGL(scan_p1, dim3(30, 3), dim3(1024), 0, stream, ca);
  hipLaunchKernelGGL(scan_p2, dim3(1, 3), dim3(64), 0, stream, ca);
  hipLaunchKernelGGL(scan_p3, dim3(30, 3), dim3(1024), 0, stream, ca);
  hipLaunchKernelGGL(scatter_b, dim3(egrid, 3), dim3(256), 0, stream, ca);
  hipLaunchKernelGGL(gather_b, dim3(egrid, 3), dim3(256), 0, stream, ca);

  hipLaunchKernelGGL(gen_proj, dim3((NGEN * 32 + 255) / 256), dim3(256), 0, stream,
                     x_gen, pw, pb, xg16_0);
  hipLaunchKernelGGL(cast_k, dim3((NBUS * 32 + 255) / 256), dim3(256), 0, stream,
                     x_bus, xb16_0, NBUS * 32);

  // ---- single upfront pack of all 3 layers (+ residual projections) ----
  const int K_l[3] = {32, 256, 256};
  const int Nbus_l[3] = {1280, 1024, 1088};
  const int Ngen_l[3] = {768, 512, 576};
  int Lbase[3], goff_l[3];
  {
    int b = 0;
    for (int l = 0; l < 3; ++l) {
      Lbase[l] = b;
      goff_l[l] = Nbus_l[l] * K_l[l];
      b += (Nbus_l[l] + Ngen_l[l]) * K_l[l];
    }
  }
  PackArgs pa = {};
  int ns = 0;
  auto add = [&](const float* src, int offel, int N_, int lg, int K) {
    pa.src[ns] = src; pa.off[ns] = offel; pa.lgN[ns] = lg;
    pa.total[ns] = K * N_; pa.K[ns] = K; ++ns;
  };
  for (int l = 0; l < 3; ++l) {
    int K = K_l[l];
    size_t sl = (size_t)K * 256;
    int L = Lbase[l], go = goff_l[l];
    add(Wl[l], L, 256, 8, K);
    add(Wr[l], L + 256 * K, 256, 8, K);
    add(Wr[l] + sl, L + 512 * K, 256, 8, K);
    add(Wl[l] + 2 * sl, L + 768 * K, 256, 8, K);
    add(Wl[l] + sl, L + go, 256, 8, K);
    add(Wr[l] + 2 * sl, L + go + 256 * K, 256, 8, K);
    if (l == 0) {
      add(rp0_w, L + 1024 * K, 256, 8, K);
      add(rp0_w + 32 * 256, L + go + 512 * K, 256, 8, K);
    } else if (l == 2) {
      add(rp2_w, L + 1024 * K, 64, 6, K);
      add(rp2_w + 256 * 64, L + go + 512 * K, 64, 6, K);
    }
  }
  hipLaunchKernelGGL(pack_multi, dim3(256, ns), dim3(256), 0, stream, pa, Wt);

  for (int l = 0; l < 3; ++l) {
    const int K = K_l[l];
    const int Nb = Nbus_l[l], Ng = Ngen_l[l];
    const u16* Ab = (l == 0) ? xb16_0 : xb16;
    const u16* Ag = (l == 0) ? xg16_0 : xg16;

    // --- merged bus+gen projection GEMM ---
    int ybus = (Nb + 127) / 128, ygen = (Ng + 127) / 128;
    hipLaunchKernelGGL(gemm_both, dim3((NBUS + 127) / 128, ybus + ygen),
                       dim3(256), 0, stream,
                       Ab, Ag, Wt + Lbase[l], goff_l[l], Pbus, Pgen, K, Nb, Ng, ybus);

    // --- fused conv + LN/residual/activation ---
    ConvP pb_;
    pb_.rpA = rp_line; pb_.srcA = sc_line; pb_.eaA = eaC0;
    pb_.xlA = Pbus; pb_.ldlA = Nb; pb_.xrA = Pbus + 256; pb_.ldrA = Nb;
    pb_.WeA = We[l]; pb_.attA = att[l]; pb_.tA = temp[l];
    pb_.rpB = rp_g2b; pb_.srcB = sc_g2b; pb_.eaB = eaC1;
    pb_.xlB = Pgen; pb_.ldlB = Ng; pb_.xrB = Pbus + 512; pb_.ldrB = Nb;
    pb_.WeB = We[l] + 1536; pb_.attB = att[l] + 256; pb_.tB = temp[l] + 1;
    ConvP pg_ = {};
    pg_.rpA = rp_b2g; pg_.srcA = sc_b2g; pg_.eaA = eaC2;
    pg_.xlA = Pbus + 768; pg_.ldlA = Nb; pg_.xrA = Pgen + 256; pg_.ldrA = Ng;
    pg_.WeA = We[l] + 3072; pg_.attA = att[l] + 512; pg_.tA = temp[l] + 2;
    pg_.rpB = nullptr;
    dim3 gb((NBUS + 3) / 4), gg((NGEN + 3) / 4), blk(256);

    if (l < 2) {
      pb_.b1 = bc[l]; pb_.b2 = bc[l] + 256; pb_.lnw = lnw[l]; pb_.lnb = lnb[l];
      pg_.b1 = bc[l] + 512; pg_.b2 = nullptr;
      pg_.lnw = lnw[l] + 256; pg_.lnb = lnb[l] + 256;
      if (l == 0) {
        pb_.res16 = Pbus + 1024; pb_.ld16 = Nb;
        pg_.res16 = Pgen + 512; pg_.ld16 = Ng;
      } else {
        pb_.res16 = xb16; pb_.ld16 = 256;   // read-before-write per node: safe
        pg_.res16 = xg16; pg_.ld16 = 256;
      }
      pb_.outf = nullptr; pb_.out16 = xb16; pb_.N = NBUS;
      pg_.outf = nullptr; pg_.out16 = xg16; pg_.N = NGEN;
      hipLaunchKernelGGL((conv_fused<0, 1>), gb, blk, 0, stream, pb_);
      hipLaunchKernelGGL((conv_fused<0, 0>), gg, blk, 0, stream, pg_);
    } else {
      pb_.b1 = bc[2]; pb_.b2 = bc[2] + 64; pb_.lnw = lnw[2]; pb_.lnb = lnb[2];
      pb_.res16 = Pbus + 1024; pb_.ld16 = Nb;
      pb_.outf = (float*)d_out; pb_.out16 = nullptr; pb_.N = NBUS;
      pg_.b1 = bc[2] + 128; pg_.b2 = nullptr; pg_.lnw = lnw[2] + 64; pg_.lnb = lnb[2] + 64;
      pg_.res16 = Pgen + 512; pg_.ld16 = Ng;
      pg_.outf = (float*)d_out + (size_t)NBUS * 64; pg_.out16 = nullptr; pg_.N = NGEN;
      hipLaunchKernelGGL((conv_fused<1, 1>), gb, blk, 0, stream, pb_);
      hipLaunchKernelGGL((conv_fused<1, 0>), gg, blk, 0, stream, pg_);
    }
  }
}

// Round 20
// 570.141 us; speedup vs baseline: 1.1115x; 1.1115x over previous
//
#include <hip/hip_runtime.h>
#include <math.h>

#define NBUS 30000
#define NGEN 6000
#define NEL 250000
#define NEG 12000

#define AS1 __attribute__((address_space(1)))
#define AS3 __attribute__((address_space(3)))

typedef unsigned short u16;
typedef __attribute__((ext_vector_type(8))) short bf16x8;
typedef __attribute__((ext_vector_type(4))) float f32x4;

__device__ __forceinline__ u16 f2b(float x) {  // fp32 -> bf16 RNE
  unsigned u = __float_as_uint(x);
  unsigned r = (u + 0x7FFFu + ((u >> 16) & 1u)) >> 16;
  return (u16)r;
}
__device__ __forceinline__ float b2f(u16 x) {
  return __uint_as_float((unsigned)x << 16);
}

__global__ void zeroi(int* __restrict__ p, int n) {
  int i = blockIdx.x * blockDim.x + threadIdx.x;
  int st = gridDim.x * blockDim.x;
  for (; i < n; i += st) p[i] = 0;
}

__global__ void cast_k(const float* __restrict__ s, u16* __restrict__ d, int n) {
  int i = blockIdx.x * 256 + threadIdx.x;
  if (i < n) d[i] = f2b(s[i]);
}

// ---------------- batched CSR build over 3 edge types ----------------
struct CsrArgs {
  const int* dst[3];
  const int* src[3];
  const float* ea[3];
  int* cnt[3];      // histogram; later reused as scatter cursor
  int* rowptr[3];
  int* eidx[3];
  int* srcC[3];
  float* eaC[3];
  int* psum[3];
  int E[3];
  int N[3];
};

__global__ void hist_b(CsrArgs a) {
  int ty = blockIdx.y;
  int i = blockIdx.x * 256 + threadIdx.x;
  if (i < a.E[ty]) atomicAdd(&a.cnt[ty][a.dst[ty][i]], 1);
}

__global__ __launch_bounds__(1024) void scan_p1(CsrArgs a) {
  int ty = blockIdx.y;
  int n = a.N[ty];
  int base = blockIdx.x * 1024;
  if (base >= n) return;
  int tid = threadIdx.x, lane = tid & 63, wv = tid >> 6;
  int i = base + tid;
  int v = (i < n) ? a.cnt[ty][i] : 0;
#pragma unroll
  for (int off = 32; off >= 1; off >>= 1) v += __shfl_xor(v, off);
  __shared__ int w[16];
  if (lane == 0) w[wv] = v;
  __syncthreads();
  if (tid < 16) {
    int t = w[tid];
#pragma unroll
    for (int off = 8; off >= 1; off >>= 1) t += __shfl_xor(t, off, 16);
    if (tid == 0) a.psum[ty][blockIdx.x] = t;
  }
}

__global__ __launch_bounds__(64) void scan_p2(CsrArgs a) {
  int ty = blockIdx.y;
  int nb = (a.N[ty] + 1023) / 1024;
  int tid = threadIdx.x;
  int v = (tid < nb) ? a.psum[ty][tid] : 0;
  int x = v;
#pragma unroll
  for (int off = 1; off < 64; off <<= 1) {
    int y = __shfl_up(x, off, 64);
    if (tid >= off) x += y;
  }
  if (tid < nb) a.psum[ty][tid] = x - v;  // exclusive
}

__global__ __launch_bounds__(1024) void scan_p3(CsrArgs a) {
  int ty = blockIdx.y;
  int n = a.N[ty];
  int base = blockIdx.x * 1024;
  if (base >= n) return;
  int tid = threadIdx.x, lane = tid & 63, wv = tid >> 6;
  int i = base + tid;
  int v = (i < n) ? a.cnt[ty][i] : 0;
  int x = v;
#pragma unroll
  for (int off = 1; off < 64; off <<= 1) {
    int y = __shfl_up(x, off, 64);
    if (lane >= off) x += y;
  }
  __shared__ int w[16];
  if (lane == 63) w[wv] = x;
  __syncthreads();
  if (tid < 16) {
    int t = w[tid];
#pragma unroll
    for (int off = 1; off < 16; off <<= 1) {
      int y = __shfl_up(t, off, 16);
      if (tid >= off) t += y;
    }
    w[tid] = t;
  }
  __syncthreads();
  int woff = (wv == 0) ? 0 : w[wv - 1];
  int incl = a.psum[ty][blockIdx.x] + woff + x;
  if (i < n) {
    a.rowptr[ty][i + 1] = incl;
    a.cnt[ty][i] = incl - v;  // cursor (exclusive)
  }
  if (i == 0) a.rowptr[ty][0] = 0;
}

__global__ void scatter_b(CsrArgs a) {
  int ty = blockIdx.y;
  int i = blockIdx.x * 256 + threadIdx.x;
  if (i < a.E[ty]) {
    int p = atomicAdd(&a.cnt[ty][a.dst[ty][i]], 1);
    a.eidx[ty][p] = i;
  }
}

__global__ void gather_b(CsrArgs a) {
  int ty = blockIdx.y;
  int i = blockIdx.x * 256 + threadIdx.x;
  if (i >= a.E[ty]) return;
  int e = a.eidx[ty][i];
  a.srcC[ty][i] = a.src[ty][e];
  const float* s = a.ea[ty] + (size_t)e * 6;
  float* d = a.eaC[ty] + (size_t)i * 8;
  float e3 = s[3];
  d[0] = s[0]; d[1] = s[1]; d[2] = s[2]; d[3] = e3; d[4] = s[4];
  d[5] = 1.f / fmaxf(e3, 1e-6f);
}

// ---------------- projections ----------------
__global__ void gen_proj(const float* __restrict__ x, const float* __restrict__ w,
                         const float* __restrict__ b, u16* __restrict__ o16) {
  int idx = blockIdx.x * blockDim.x + threadIdx.x;
  if (idx >= NGEN * 32) return;
  int i = idx >> 5, c = idx & 31;
  float acc = b[c];
#pragma unroll
  for (int k = 0; k < 16; ++k) acc += x[i * 16 + k] * w[k * 32 + c];
  o16[idx] = f2b(acc);
}

struct PackArgs {
  const float* src[24];
  int off[24];
  int lgN[24];
  int total[24];
  int K[24];
};
__global__ void pack_multi(PackArgs a, u16* __restrict__ Wt) {
  int j = blockIdx.y;
  int idx = blockIdx.x * 256 + threadIdx.x;
  if (idx >= a.total[j]) return;
  int N1 = (1 << a.lgN[j]) - 1;
  int n = idx & N1;
  int k = idx >> a.lgN[j];
  Wt[(size_t)a.off[j] + (size_t)n * a.K[j] + k] = f2b(a.src[j][idx]);
}

// Merged bus+gen GEMM: global_load_lds w=16, XOR swizzle.
__global__ __launch_bounds__(256) void gemm_both(
    const u16* __restrict__ Ab, const u16* __restrict__ Ag,
    const u16* __restrict__ Wt, int goff,
    u16* __restrict__ Cb, u16* __restrict__ Cg,
    int K, int Nb, int Ng, int ybus)
{
  __shared__ __align__(16) u16 As[128 * 32];
  __shared__ __align__(16) u16 Bs[128 * 32];
  const int t = threadIdx.x;
  const int w = t >> 6, lane = t & 63;
  const u16* A; const u16* W; u16* C; int M, Ncols, bn;
  if ((int)blockIdx.y < ybus) {
    A = Ab; W = Wt; C = Cb; M = NBUS; Ncols = Nb; bn = blockIdx.y * 128;
  } else {
    A = Ag; W = Wt + goff; C = Cg; M = NGEN; Ncols = Ng; bn = (blockIdx.y - ybus) * 128;
  }
  const int bm = blockIdx.x * 128;
  if (bm >= M) return;
  const int wm = (w & 1) * 64, wn = (w >> 1) * 64;
  const int lr = lane & 15, q = lane >> 4;
  const int srow = lane >> 2;
  const int blk = (lane & 3) ^ (srow & 3);
  f32x4 acc[4][4] = {};
  for (int k0 = 0; k0 < K; k0 += 32) {
#pragma unroll
    for (int sseg = 0; sseg < 2; ++sseg) {
      int seg = w + (sseg << 2);
      int row = (seg << 4) + srow;
      int ga = bm + row; if (ga > M - 1) ga = M - 1;
      const u16* gpa = A + (size_t)ga * K + k0 + (blk << 3);
      __builtin_amdgcn_global_load_lds((AS1 void*)gpa, (AS3 void*)(As + (seg << 9)),
                                       16, 0, 0);
      int gb = bn + row;
      const u16* gpb = W + (size_t)gb * K + k0 + (blk << 3);
      __builtin_amdgcn_global_load_lds((AS1 void*)gpb, (AS3 void*)(Bs + (seg << 9)),
                                       16, 0, 0);
    }
    __syncthreads();
    bf16x8 af[4], bg[4];
#pragma unroll
    for (int i = 0; i < 4; ++i) {
      int r = wm + i * 16 + lr;
      af[i] = *(const bf16x8*)&As[(r << 5) + ((q ^ (r & 3)) << 3)];
    }
#pragma unroll
    for (int j = 0; j < 4; ++j) {
      int r = wn + j * 16 + lr;
      bg[j] = *(const bf16x8*)&Bs[(r << 5) + ((q ^ (r & 3)) << 3)];
    }
#pragma unroll
    for (int i = 0; i < 4; ++i)
#pragma unroll
      for (int j = 0; j < 4; ++j)
        acc[i][j] = __builtin_amdgcn_mfma_f32_16x16x32_bf16(
            af[i], bg[j], acc[i][j], 0, 0, 0);
    __syncthreads();
  }
#pragma unroll
  for (int i = 0; i < 4; ++i) {
    int row0 = bm + wm + i * 16 + q * 4;
#pragma unroll
    for (int j = 0; j < 4; ++j) {
      int col = bn + wn + j * 16 + lr;
      if (col < Ncols) {
#pragma unroll
        for (int r = 0; r < 4; ++r) {
          int row = row0 + r;
          if (row < M) C[(size_t)row * Ncols + col] = f2b(acc[i][j][r]);
        }
      }
    }
  }
}

// ---------------- fused GATv2 conv (online softmax, 2-state ILP) ----------------
__device__ __forceinline__ f32x4 conv_set(
    int node, int lane, const int* __restrict__ rp,
    const int* __restrict__ srcc, const float* __restrict__ eac,
    const u16* __restrict__ xl, int ldl,
    const u16* __restrict__ xr, int ldr,
    const float* __restrict__ We, const float* __restrict__ att,
    const float* __restrict__ tptr)
{
  int c0 = lane << 2;
  float4 w0 = *(const float4*)(We + c0);
  float4 w1 = *(const float4*)(We + 256 + c0);
  float4 w2 = *(const float4*)(We + 512 + c0);
  float4 w3 = *(const float4*)(We + 768 + c0);
  float4 w4 = *(const float4*)(We + 1024 + c0);
  float4 w5 = *(const float4*)(We + 1280 + c0);
  float4 av = *(const float4*)(att + c0);
  float temp = *tptr;
  ushort4 r16 = *(const ushort4*)(xr + (size_t)node * ldr + c0);
  float rx0 = b2f(r16.x), rx1 = b2f(r16.y), rx2 = b2f(r16.z), rx3 = b2f(r16.w);
  int beg = rp[node], end = rp[node + 1];
  float mxa = -INFINITY, dena = 0.f;
  float mxb = -INFINITY, denb = 0.f;
  f32x4 aca = {0.f, 0.f, 0.f, 0.f};
  f32x4 acb = {0.f, 0.f, 0.f, 0.f};

  auto edge_upd = [&](int i, float& mx, float& den, f32x4& acc) {
    int s = srcc[i];
    const float* e = eac + (size_t)i * 8;
    float4 ev = *(const float4*)e;
    float2 e2v = *(const float2*)(e + 4);
    float e5 = temp * e2v.y;
    ushort4 l16 = *(const ushort4*)(xl + (size_t)s * ldl + c0);
    float lx0 = b2f(l16.x), lx1 = b2f(l16.y), lx2 = b2f(l16.z), lx3 = b2f(l16.w);
    float m0 = lx0 + rx0 + ev.x*w0.x + ev.y*w1.x + ev.z*w2.x + ev.w*w3.x + e2v.x*w4.x + e5*w5.x;
    float m1 = lx1 + rx1 + ev.x*w0.y + ev.y*w1.y + ev.z*w2.y + ev.w*w3.y + e2v.x*w4.y + e5*w5.y;
    float m2 = lx2 + rx2 + ev.x*w0.z + ev.y*w1.z + ev.z*w2.z + ev.w*w3.z + e2v.x*w4.z + e5*w5.z;
    float m3 = lx3 + rx3 + ev.x*w0.w + ev.y*w1.w + ev.z*w2.w + ev.w*w3.w + e2v.x*w4.w + e5*w5.w;
    m0 = fmaxf(m0, 0.2f * m0);
    m1 = fmaxf(m1, 0.2f * m1);
    m2 = fmaxf(m2, 0.2f * m2);
    m3 = fmaxf(m3, 0.2f * m3);
    float p = m0*av.x + m1*av.y + m2*av.z + m3*av.w;
    p += __shfl_xor(p, 1);
    p += __shfl_xor(p, 2);
    p += __shfl_xor(p, 4);
    p += __shfl_xor(p, 8);
    float nm = fmaxf(mx, p);
    float sc = __expf(mx - nm);
    float wq = __expf(p - nm);
    mx = nm;
    den = den * sc + wq;
    acc[0] = acc[0] * sc + wq * lx0;
    acc[1] = acc[1] * sc + wq * lx1;
    acc[2] = acc[2] * sc + wq * lx2;
    acc[3] = acc[3] * sc + wq * lx3;
  };

  int i = beg;
  if ((end - beg) & 1) { edge_upd(i, mxa, dena, aca); ++i; }
  for (; i < end; i += 2) {
    edge_upd(i, mxa, dena, aca);
    edge_upd(i + 1, mxb, denb, acb);
  }
  float nm = fmaxf(mxa, mxb);
  f32x4 r = {0.f, 0.f, 0.f, 0.f};
  if (nm > -INFINITY) {
    float sa = __expf(mxa - nm), sb = __expf(mxb - nm);
    float den = dena * sa + denb * sb;
    float inv = 1.f / (den + 1e-16f);
    r[0] = (aca[0] * sa + acb[0] * sb) * inv;
    r[1] = (aca[1] * sa + acb[1] * sb) * inv;
    r[2] = (aca[2] * sa + acb[2] * sb) * inv;
    r[3] = (aca[3] * sa + acb[3] * sb) * inv;
  }
  return r;
}

struct ConvP {
  const int *rpA, *srcA; const float* eaA;
  const u16 *xlA; int ldlA; const u16 *xrA; int ldrA;
  const float *WeA, *attA, *tA;
  const int *rpB, *srcB; const float* eaB;
  const u16 *xlB; int ldlB; const u16 *xrB; int ldrB;
  const float *WeB, *attB, *tB;
  const float *b1, *b2;        // conv bias(es)
  const float *lnw, *lnb;
  const u16 *res16; int ld16;  // bf16 residual (P column or state buffer)
  float *outf;                 // MODE1: d_out base
  u16 *out16;                  // MODE0: bf16 state out
  int N;
};

// MODE 0: LN256 + bf16-residual + ELU, write bf16 state.
// MODE 1: head-mean + LN64 + bf16-residual, write d_out (fp32).
template<int MODE, int HASB>
__global__ __launch_bounds__(256) void conv_fused(ConvP p) {
  int node = blockIdx.x * 4 + (threadIdx.x >> 6);
  int lane = threadIdx.x & 63;
  if (node >= p.N) return;
  f32x4 o = conv_set(node, lane, p.rpA, p.srcA, p.eaA, p.xlA, p.ldlA,
                     p.xrA, p.ldrA, p.WeA, p.attA, p.tA);
  if (HASB) {
    if (p.rpB[node] < p.rpB[node + 1]) {  // skip empty set-B (uniform branch)
      f32x4 ob = conv_set(node, lane, p.rpB, p.srcB, p.eaB, p.xlB, p.ldlB,
                          p.xrB, p.ldrB, p.WeB, p.attB, p.tB);
      o[0] += ob[0]; o[1] += ob[1]; o[2] += ob[2]; o[3] += ob[3];
    }
  }
  if (MODE == 0) {
    int c = lane << 2;
    float4 bb = *(const float4*)(p.b1 + c);
    float v0 = o[0] + bb.x, v1 = o[1] + bb.y, v2 = o[2] + bb.z, v3 = o[3] + bb.w;
    if (p.b2) {
      float4 b2v = *(const float4*)(p.b2 + c);
      v0 += b2v.x; v1 += b2v.y; v2 += b2v.z; v3 += b2v.w;
    }
    float s = v0 + v1 + v2 + v3;
#pragma unroll
    for (int m = 32; m >= 1; m >>= 1) s += __shfl_xor(s, m);
    float mu = s * (1.f / 256.f);
    float d0 = v0 - mu, d1 = v1 - mu, d2 = v2 - mu, d3 = v3 - mu;
    float q = d0*d0 + d1*d1 + d2*d2 + d3*d3;
#pragma unroll
    for (int m = 32; m >= 1; m >>= 1) q += __shfl_xor(q, m);
    float rs = rsqrtf(q * (1.f / 256.f) + 1e-5f);
    float4 lw = *(const float4*)(p.lnw + c);
    float4 lb = *(const float4*)(p.lnb + c);
    float y0 = d0 * rs * lw.x + lb.x;
    float y1 = d1 * rs * lw.y + lb.y;
    float y2 = d2 * rs * lw.z + lb.z;
    float y3 = d3 * rs * lw.w + lb.w;
    ushort4 r = *(const ushort4*)(p.res16 + (size_t)node * p.ld16 + c);
    y0 += b2f(r.x); y1 += b2f(r.y); y2 += b2f(r.z); y3 += b2f(r.w);
    y0 = (y0 > 0.f) ? y0 : expm1f(y0);
    y1 = (y1 > 0.f) ? y1 : expm1f(y1);
    y2 = (y2 > 0.f) ? y2 : expm1f(y2);
    y3 = (y3 > 0.f) ? y3 : expm1f(y3);
    ushort4 o16;
    o16.x = f2b(y0); o16.y = f2b(y1); o16.z = f2b(y2); o16.w = f2b(y3);
    *(ushort4*)(p.out16 + (size_t)node * 256 + c) = o16;
  } else {
    // head mean: sum over the 4 head groups (lanes xor 16, 32)
    float h0 = o[0], h1 = o[1], h2 = o[2], h3 = o[3];
    h0 += __shfl_xor(h0, 16); h0 += __shfl_xor(h0, 32);
    h1 += __shfl_xor(h1, 16); h1 += __shfl_xor(h1, 32);
    h2 += __shfl_xor(h2, 16); h2 += __shfl_xor(h2, 32);
    h3 += __shfl_xor(h3, 16); h3 += __shfl_xor(h3, 32);
    int cc = (lane & 15) << 2;
    float4 bb = *(const float4*)(p.b1 + cc);
    float v0 = 0.25f * h0 + bb.x, v1 = 0.25f * h1 + bb.y;
    float v2 = 0.25f * h2 + bb.z, v3 = 0.25f * h3 + bb.w;
    if (p.b2) {
      float4 b2v = *(const float4*)(p.b2 + cc);
      v0 += b2v.x; v1 += b2v.y; v2 += b2v.z; v3 += b2v.w;
    }
    float s = v0 + v1 + v2 + v3;
#pragma unroll
    for (int m = 8; m >= 1; m >>= 1) s += __shfl_xor(s, m);
    float mu = s * (1.f / 64.f);
    float d0 = v0 - mu, d1 = v1 - mu, d2 = v2 - mu, d3 = v3 - mu;
    float q = d0*d0 + d1*d1 + d2*d2 + d3*d3;
#pragma unroll
    for (int m = 8; m >= 1; m >>= 1) q += __shfl_xor(q, m);
    float rs = rsqrtf(q * (1.f / 64.f) + 1e-5f);
    float4 lw = *(const float4*)(p.lnw + cc);
    float4 lb = *(const float4*)(p.lnb + cc);
    ushort4 r = *(const ushort4*)(p.res16 + (size_t)node * p.ld16 + cc);
    float y0 = d0 * rs * lw.x + lb.x + b2f(r.x);
    float y1 = d1 * rs * lw.y + lb.y + b2f(r.y);
    float y2 = d2 * rs * lw.z + lb.z + b2f(r.z);
    float y3 = d3 * rs * lw.w + lb.w + b2f(r.w);
    if (lane < 16)
      *(float4*)(p.outf + (size_t)node * 64 + cc) = make_float4(y0, y1, y2, y3);
  }
}

extern "C" void kernel_launch(void* const* d_in, const int* in_sizes, int n_in,
                              void* d_out, int out_size, void* d_ws, size_t ws_size,
                              hipStream_t stream) {
  const float* x_bus = (const float*)d_in[0];
  const float* x_gen = (const float*)d_in[1];
  const float* ea[3] = {(const float*)d_in[2], (const float*)d_in[3], (const float*)d_in[4]};
  const float* pw = (const float*)d_in[5];
  const float* pb = (const float*)d_in[6];
  const float* Wl[3] = {(const float*)d_in[7], (const float*)d_in[15], (const float*)d_in[23]};
  const float* Wr[3] = {(const float*)d_in[8], (const float*)d_in[16], (const float*)d_in[24]};
  const float* We[3] = {(const float*)d_in[9], (const float*)d_in[17], (const float*)d_in[25]};
  const float* att[3] = {(const float*)d_in[10], (const float*)d_in[18], (const float*)d_in[26]};
  const float* bc[3] = {(const float*)d_in[11], (const float*)d_in[19], (const float*)d_in[27]};
  const float* temp[3] = {(const float*)d_in[12], (const float*)d_in[20], (const float*)d_in[28]};
  const float* lnw[3] = {(const float*)d_in[13], (const float*)d_in[21], (const float*)d_in[29]};
  const float* lnb[3] = {(const float*)d_in[14], (const float*)d_in[22], (const float*)d_in[30]};
  const float* rp0_w = (const float*)d_in[31];
  const float* rp2_w = (const float*)d_in[33];
  const int* srcs[3] = {(const int*)d_in[35], (const int*)d_in[37], (const int*)d_in[39]};
  const int* dsts[3] = {(const int*)d_in[36], (const int*)d_in[38], (const int*)d_in[40]};

  float* ws = (float*)d_ws;
  size_t off = 0;
  auto alloc = [&](size_t n) { float* p = ws + off; off += n; return p; };
  u16* xb16_0 = (u16*)alloc((size_t)NBUS * 16);
  u16* xg16_0 = (u16*)alloc((size_t)NGEN * 16);
  u16* xb16 = (u16*)alloc((size_t)NBUS * 128);
  u16* xg16 = (u16*)alloc((size_t)NGEN * 128);
  u16* Pbus = (u16*)alloc((size_t)NBUS * 640);
  u16* Pgen = (u16*)alloc((size_t)NGEN * 384);
  u16* Wt = (u16*)alloc((size_t)886000 / 2);  // 884736 packed elements + pad
  float* eaC0 = alloc((size_t)NEL * 8);
  float* eaC1 = alloc((size_t)NEG * 8);
  float* eaC2 = alloc((size_t)NEG * 8);
  int* cw_all = (int*)alloc(NBUS + NBUS + NGEN);  // 3 histograms, contiguous
  int* rp_line = (int*)alloc(NBUS + 1);
  int* rp_g2b = (int*)alloc(NBUS + 1);
  int* rp_b2g = (int*)alloc(NGEN + 1);
  int* ei_line = (int*)alloc(NEL);
  int* ei_g2b = (int*)alloc(NEG);
  int* ei_b2g = (int*)alloc(NEG);
  int* sc_line = (int*)alloc(NEL);
  int* sc_g2b = (int*)alloc(NEG);
  int* sc_b2g = (int*)alloc(NEG);
  int* psum = (int*)alloc(3 * 32);
  (void)ws_size; (void)in_sizes; (void)n_in; (void)out_size;

  CsrArgs ca;
  for (int t = 0; t < 3; ++t) { ca.dst[t] = dsts[t]; ca.src[t] = srcs[t]; ca.ea[t] = ea[t]; }
  ca.cnt[0] = cw_all; ca.cnt[1] = cw_all + NBUS; ca.cnt[2] = cw_all + 2 * NBUS;
  ca.rowptr[0] = rp_line; ca.rowptr[1] = rp_g2b; ca.rowptr[2] = rp_b2g;
  ca.eidx[0] = ei_line; ca.eidx[1] = ei_g2b; ca.eidx[2] = ei_b2g;
  ca.srcC[0] = sc_line; ca.srcC[1] = sc_g2b; ca.srcC[2] = sc_b2g;
  ca.eaC[0] = eaC0; ca.eaC[1] = eaC1; ca.eaC[2] = eaC2;
  ca.psum[0] = psum; ca.psum[1] = psum + 32; ca.psum[2] = psum + 64;
  ca.E[0] = NEL; ca.E[1] = NEG; ca.E[2] = NEG;
  ca.N[0] = NBUS; ca.N[1] = NBUS; ca.N[2] = NGEN;

  int egrid = (NEL + 255) / 256;
  hipLaunchKernelGGL(zeroi, dim3(64), dim3(1024), 0, stream, cw_all, 2 * NBUS + NGEN);
  hipLaunchKernelGGL(hist_b, dim3(egrid, 3), dim3(256), 0, stream, ca);
  hipLaunchKernelGGL(scan_p1, dim3(30, 3), dim3(1024), 0, stream, ca);
  hipLaunchKernelGGL(scan_p2, dim3(1, 3), dim3(64), 0, stream, ca);
  hipLaunchKernelGGL(scan_p3, dim3(30, 3), dim3(1024), 0, stream, ca);
  hipLaunchKernelGGL(scatter_b, dim3(egrid, 3), dim3(256), 0, stream, ca);
  hipLaunchKernelGGL(gather_b, dim3(egrid, 3), dim3(256), 0, stream, ca);

  hipLaunchKernelGGL(gen_proj, dim3((NGEN * 32 + 255) / 256), dim3(256), 0, stream,
                     x_gen, pw, pb, xg16_0);
  hipLaunchKernelGGL(cast_k, dim3((NBUS * 32 + 255) / 256), dim3(256), 0, stream,
                     x_bus, xb16_0, NBUS * 32);

  // ---- single upfront pack of all 3 layers (+ residual projections) ----
  const int K_l[3] = {32, 256, 256};
  const int Nbus_l[3] = {1280, 1024, 1088};
  const int Ngen_l[3] = {768, 512, 576};
  int Lbase[3], goff_l[3];
  {
    int b = 0;
    for (int l = 0; l < 3; ++l) {
      Lbase[l] = b;
      goff_l[l] = Nbus_l[l] * K_l[l];
      b += (Nbus_l[l] + Ngen_l[l]) * K_l[l];
    }
  }
  PackArgs pa = {};
  int ns = 0;
  auto add = [&](const float* src, int offel, int N_, int lg, int K) {
    pa.src[ns] = src; pa.off[ns] = offel; pa.lgN[ns] = lg;
    pa.total[ns] = K * N_; pa.K[ns] = K; ++ns;
  };
  for (int l = 0; l < 3; ++l) {
    int K = K_l[l];
    size_t sl = (size_t)K * 256;
    int L = Lbase[l], go = goff_l[l];
    add(Wl[l], L, 256, 8, K);
    add(Wr[l], L + 256 * K, 256, 8, K);
    add(Wr[l] + sl, L + 512 * K, 256, 8, K);
    add(Wl[l] + 2 * sl, L + 768 * K, 256, 8, K);
    add(Wl[l] + sl, L + go, 256, 8, K);
    add(Wr[l] + 2 * sl, L + go + 256 * K, 256, 8, K);
    if (l == 0) {
      add(rp0_w, L + 1024 * K, 256, 8, K);
      add(rp0_w + 32 * 256, L + go + 512 * K, 256, 8, K);
    } else if (l == 2) {
      add(rp2_w, L + 1024 * K, 64, 6, K);
      add(rp2_w + 256 * 64, L + go + 512 * K, 64, 6, K);
    }
  }
  hipLaunchKernelGGL(pack_multi, dim3(256, ns), dim3(256), 0, stream, pa, Wt);

  for (int l = 0; l < 3; ++l) {
    const int K = K_l[l];
    const int Nb = Nbus_l[l], Ng = Ngen_l[l];
    const u16* Ab = (l == 0) ? xb16_0 : xb16;
    const u16* Ag = (l == 0) ? xg16_0 : xg16;

    // --- merged bus+gen projection GEMM ---
    int ybus = (Nb + 127) / 128, ygen = (Ng + 127) / 128;
    hipLaunchKernelGGL(gemm_both, dim3((NBUS + 127) / 128, ybus + ygen),
                       dim3(256), 0, stream,
                       Ab, Ag, Wt + Lbase[l], goff_l[l], Pbus, Pgen, K, Nb, Ng, ybus);

    // --- fused conv + LN/residual/activation ---
    ConvP pb_;
    pb_.rpA = rp_line; pb_.srcA = sc_line; pb_.eaA = eaC0;
    pb_.xlA = Pbus; pb_.ldlA = Nb; pb_.xrA = Pbus + 256; pb_.ldrA = Nb;
    pb_.WeA = We[l]; pb_.attA = att[l]; pb_.tA = temp[l];
    pb_.rpB = rp_g2b; pb_.srcB = sc_g2b; pb_.eaB = eaC1;
    pb_.xlB = Pgen; pb_.ldlB = Ng; pb_.xrB = Pbus + 512; pb_.ldrB = Nb;
    pb_.WeB = We[l] + 1536; pb_.attB = att[l] + 256; pb_.tB = temp[l] + 1;
    ConvP pg_ = {};
    pg_.rpA = rp_b2g; pg_.srcA = sc_b2g; pg_.eaA = eaC2;
    pg_.xlA = Pbus + 768; pg_.ldlA = Nb; pg_.xrA = Pgen + 256; pg_.ldrA = Ng;
    pg_.WeA = We[l] + 3072; pg_.attA = att[l] + 512; pg_.tA = temp[l] + 2;
    pg_.rpB = nullptr;
    dim3 gb((NBUS + 3) / 4), gg((NGEN + 3) / 4), blk(256);

    if (l < 2) {
      pb_.b1 = bc[l]; pb_.b2 = bc[l] + 256; pb_.lnw = lnw[l]; pb_.lnb = lnb[l];
      pg_.b1 = bc[l] + 512; pg_.b2 = nullptr;
      pg_.lnw = lnw[l] + 256; pg_.lnb = lnb[l] + 256;
      if (l == 0) {
        pb_.res16 = Pbus + 1024; pb_.ld16 = Nb;
        pg_.res16 = Pgen + 512; pg_.ld16 = Ng;
      } else {
        pb_.res16 = xb16; pb_.ld16 = 256;   // read-before-write per node: safe
        pg_.res16 = xg16; pg_.ld16 = 256;
      }
      pb_.outf = nullptr; pb_.out16 = xb16; pb_.N = NBUS;
      pg_.outf = nullptr; pg_.out16 = xg16; pg_.N = NGEN;
      hipLaunchKernelGGL((conv_fused<0, 1>), gb, blk, 0, stream, pb_);
      hipLaunchKernelGGL((conv_fused<0, 0>), gg, blk, 0, stream, pg_);
    } else {
      pb_.b1 = bc[2]; pb_.b2 = bc[2] + 64; pb_.lnw = lnw[2]; pb_.lnb = lnb[2];
      pb_.res16 = Pbus + 1024; pb_.ld16 = Nb;
      pb_.outf = (float*)d_out; pb_.out16 = nullptr; pb_.N = NBUS;
      pg_.b1 = bc[2] + 128; pg_.b2 = nullptr; pg_.lnw = lnw[2] + 64; pg_.lnb = lnb[2] + 64;
      pg_.res16 = Pgen + 512; pg_.ld16 = Ng;
      pg_.outf = (float*)d_out + (size_t)NBUS * 64; pg_.out16 = nullptr; pg_.N = NGEN;
      hipLaunchKernelGGL((conv_fused<1, 1>), gb, blk, 0, stream, pb_);
      hipLaunchKernelGGL((conv_fused<1, 0>), gg, blk, 0, stream, pg_);
    }
  }
}